// Round 19
// baseline (69.450 us; speedup 1.0000x reference)
//
#include <hip/hip_runtime.h>
#include <math.h>

// CTC loss (per-step-normalized fwd/bwd), B=128, C=512, T=512, S=128, L=257.
// Round-19: gather-transpose pre-pass. The scan's per-lane row gathers
// (64 distinct 2KB-apart lines PER INSTRUCTION on the shared per-CU TA pipe)
// survived every batching attempt (r7-r18). Fix the LAYOUT instead:
//   ctc_xpose builds Px[b][t][k] = P[b][seq[b][k]][t] (k=128 -> blank row),
//   fully parallel, LDS-tiled, both global sides coalesced (~2-5us).
// The scan then reads ONE coalesced float2 per lane per step (p1,p3) + a
// uniform blank load: ~40 line-touches/slot vs ~768. Off-phase = stores only.
// Scan structure = r18 (2-wave pairing, 16-step slots, lgkmcnt-only barrier).
// Combine/final: r15 verbatim. Identity (r4-r18): lh_t = sigma*D/(S*R).
// fp32 Px (exact); bf16 rows; fp64 block accumulation; no NaN possible.

#define BB 128
#define CC 512
#define TT 512
#define SS 128
#define LL 257
#define LPADH 260   // bf16 (ushort) elements per row
#define PXW 132     // Px row stride in floats (128 labels + blank + pad)

typedef unsigned int  uint;
typedef unsigned short ushort;

// ---- fp32 DPP helpers (gfx9 controls; validated on gfx950 rounds 3-18) ----
template<int CTRL>
__device__ __forceinline__ float dpp0_f32(float x){
    int v = __builtin_bit_cast(int, x);
    int r = __builtin_amdgcn_update_dpp(0, v, CTRL, 0xF, 0xF, true);
    return __builtin_bit_cast(float, r);
}
__device__ __forceinline__ float shfl_up1_f32(float x){ return dpp0_f32<0x138>(x); }
__device__ __forceinline__ float red8f(float x){
    x += dpp0_f32<0x111>(x);
    x += dpp0_f32<0x112>(x);
    x += dpp0_f32<0x114>(x);
    return x;
}
__device__ __forceinline__ float tail3f(float x){
    x += dpp0_f32<0x118>(x);
    x += dpp0_f32<0x142>(x);
    x += dpp0_f32<0x143>(x);
    return x;
}
__device__ __forceinline__ float full64f(float x){ return tail3f(red8f(x)); }
__device__ __forceinline__ float readlane63_f32(float x){
    int v = __builtin_bit_cast(int, x);
    return __builtin_bit_cast(float, __builtin_amdgcn_readlane(v, 63));
}
__device__ __forceinline__ float pow2if(int e){
    return __builtin_bit_cast(float, (127 + e) << 23);
}
// pack two fp32 -> bf16 pair via one v_perm_b32 (truncation)
__device__ __forceinline__ uint pk_bf16(float lo, float hi){
    return __builtin_amdgcn_perm(__builtin_bit_cast(uint, hi),
                                 __builtin_bit_cast(uint, lo), 0x07060302u);
}
__device__ __forceinline__ float up_lo(uint u){ return __builtin_bit_cast(float, u << 16); }
__device__ __forceinline__ float up_hi(uint u){ return __builtin_bit_cast(float, u & 0xFFFF0000u); }
__device__ __forceinline__ float up_us(ushort u){ return __builtin_bit_cast(float, ((uint)u) << 16); }
template<int CTRL>
__device__ __forceinline__ double dpp0_f64(double x){
    int2 v = __builtin_bit_cast(int2, x);
    int2 r;
    r.x = __builtin_amdgcn_update_dpp(0, v.x, CTRL, 0xF, 0xF, true);
    r.y = __builtin_amdgcn_update_dpp(0, v.y, CTRL, 0xF, 0xF, true);
    return __builtin_bit_cast(double, r);
}
__device__ __forceinline__ double full64d(double x){
    x += dpp0_f64<0x111>(x); x += dpp0_f64<0x112>(x); x += dpp0_f64<0x114>(x);
    x += dpp0_f64<0x118>(x); x += dpp0_f64<0x142>(x); x += dpp0_f64<0x143>(x);
    return x;
}

// LDS-only barrier (r18): order the state handoff without draining vmem.
__device__ __forceinline__ void lds_barrier(){
    asm volatile("s_waitcnt lgkmcnt(0)" ::: "memory");
    __builtin_amdgcn_s_barrier();
    __builtin_amdgcn_sched_barrier(0);
    asm volatile("" ::: "memory");
}

// =================== gather-transpose pre-pass ===================
// Px[b][t][k] = P[b][seq[b][k]][t], k=0..127; Px[b][t][128] = blank row.
// Block (b, tc): t0 = tc*64. Load coalesced along t into LDS, store
// coalesced along k. tile pad 65 -> 2-way-max bank aliasing (free).
__global__ __launch_bounds__(256)
void ctc_xpose(const float* __restrict__ P, const int* __restrict__ seqg,
               const int* __restrict__ blankp, float* __restrict__ Px)
{
    __shared__ float tile[129][65];
    const int b = blockIdx.x, t0 = blockIdx.y * 64;
    const int tid = threadIdx.x;
    const int blank = blankp[0];
    const int* sq = seqg + b*SS;
    const float* Pb = P + (size_t)b*(CC*TT);

    #pragma unroll
    for (int k0 = 0; k0 < 144; k0 += 16) {
        int k = k0 + (tid >> 4);
        if (k < 129) {
            int row = (k < 128) ? sq[k] : blank;
            int tl = (tid & 15) << 2;
            float4 v = *reinterpret_cast<const float4*>(
                           Pb + (size_t)row*TT + t0 + tl);
            tile[k][tl]   = v.x; tile[k][tl+1] = v.y;
            tile[k][tl+2] = v.z; tile[k][tl+3] = v.w;
        }
    }
    __syncthreads();
    #pragma unroll
    for (int pass = 0; pass < 32; ++pass) {
        int tl = (pass << 1) + (tid >> 7);    // 0..63
        int k  = tid & 127;
        float* dst = Px + ((size_t)b*TT + t0 + tl) * PXW;
        dst[k] = tile[k][tl];
        if (k == 0) dst[128] = tile[128][tl];
    }
}

// ============ 2-wave scan; 16-step slots; coalesced Px loads ============
template<bool REV>
__device__ __forceinline__ void scan_body(
    int b, int wv, int l, const float* __restrict__ Px,
    const int* __restrict__ seqg,
    ushort* __restrict__ W, ushort* __restrict__ W4, int* __restrict__ Eb)
{
    __shared__ float4 st4[64];
    __shared__ float  st1[64];
    __shared__ float  scSh[1];

    const bool is63 = (l == 63);
    const int* sq = seqg + b*SS;

    float m1, m3;
    if (!REV) {
        int r1 = sq[2*l], r3 = sq[2*l+1];
        int ip = (l==0) ? 0 : (2*l-1);
        m1 = (l==0) ? 1.f : ((r1 != sq[ip]) ? 1.f : 0.f);
        m3 = (r3 != r1) ? 1.f : 0.f;
    } else {
        int r1 = sq[SS-1-2*l], r3 = sq[SS-2-2*l];
        int ip = (l==0) ? 0 : (SS-2*l);
        m1 = (l==0) ? 1.f : ((r1 != sq[ip]) ? 1.f : 0.f);
        m3 = (r3 != r1) ? 1.f : 0.f;
    }
    const float* PxB = Px + (size_t)b*TT*PXW;
    const int koff = REV ? (126 - 2*l) : (2*l);   // float2 base per lane
    int* EbB = Eb + b*64;

    const int tm0=(4*l+769)>>1, tm1=(4*l+770)>>1, tm2=(4*l+771)>>1, tm3=(4*l+772)>>1;

    float a0=0.f,a1=0.f,a2=0.f,a3=0.f,a4=0.f;
    float scNext = 1.f, Sfull = 0.f;
    const float u0i = (l==0) ? 1.f : 0.f;
    float2 q12[16]; float qb[16];
    uint sbLo[16], sbHi[16]; float s4f[16];

// coalesced per-step loads for slot ss: lane l float2 {p1,p3} + uniform blank
#define LOADPX(ss)                                                          \
  { _Pragma("unroll")                                                       \
    for (int j=0;j<16;++j){                                                 \
      const int i_ = 16*(ss)+j;                                             \
      const int t_ = REV ? (TT-1-i_) : i_;                                  \
      const float* rowp_ = PxB + (size_t)t_*PXW;                            \
      q12[j] = *reinterpret_cast<const float2*>(rowp_ + koff);              \
      qb[j]  = rowp_[128];                                                  \
    } }

#define STEP16(ss, j, FIRSTF, MASKF)                                        \
  {                                                                         \
    const int i = 16*(ss) + (j);                                            \
    float u0,u1,u2,u3,u4;                                                   \
    if (FIRSTF) { u0=u0i; u1=u0i; u2=0.f; u3=0.f; u4=0.f; }                 \
    else {                                                                  \
      float e3u = shfl_up1_f32(a3);                                         \
      u0 = a0 + e3u; u1 = (a1+a0) + m1*e3u; u2 = a2+a1;                     \
      u3 = (a3+a2) + m3*a1; u4 = a4+a3;                                     \
      if (MASKF) {                                                          \
        if (i >= tm0) u0 = 0.f;                                             \
        if (i >= tm1) u1 = 0.f;                                             \
        if (i >= tm2) u2 = 0.f;                                             \
        if (i >= tm3) u3 = 0.f;                                             \
      }                                                                     \
    }                                                                       \
    float pB = qb[j];                                                       \
    float pq = REV ? q12[j].y : q12[j].x;                                   \
    float pr = REV ? q12[j].x : q12[j].y;                                   \
    if (((j)&7)==0) { pB*=scNext; pq*=scNext; pr*=scNext; }                 \
    float n0=u0*pB, n1=u1*pq, n2=u2*pB, n3=u3*pr, n4=u4*pB;                 \
    sbLo[j]=pk_bf16(n0,n1); sbHi[j]=pk_bf16(n2,n3); s4f[j]=n4;              \
    if (((j)&7)==5) {                                                       \
      float part=(n0+n1)+(n2+n3); if (is63) part+=n4;                       \
      Sfull = full64f(part);                                                \
    }                                                                       \
    if (((j)&7)==7) {                                                       \
      float Su = readlane63_f32(Sfull);                                     \
      int ex = (__builtin_bit_cast(int, Su) >> 23) & 0xFF;                  \
      int e = (ex==0) ? 0 : (ex-127);                                       \
      e = e < -120 ? -120 : (e > 120 ? 120 : e);                            \
      scNext = pow2if(-e);                                                  \
      const int g_ = i >> 3;                                                \
      if (REV && l==0 && g_+1 < 64) EbB[g_+1] = e;                          \
    }                                                                       \
    a0=n0; a1=n1; a2=n2; a3=n3; a4=n4;                                      \
  }

#define RG2(ss, FIRSTF, MASKF)                                              \
    STEP16(ss,0,FIRSTF,MASKF) STEP16(ss,1,false,MASKF)                      \
    STEP16(ss,2,false,MASKF)  STEP16(ss,3,false,MASKF)                      \
    STEP16(ss,4,false,MASKF)  STEP16(ss,5,false,MASKF)                      \
    STEP16(ss,6,false,MASKF)  STEP16(ss,7,false,MASKF)                      \
    STEP16(ss,8,false,MASKF)  STEP16(ss,9,false,MASKF)                      \
    STEP16(ss,10,false,MASKF) STEP16(ss,11,false,MASKF)                     \
    STEP16(ss,12,false,MASKF) STEP16(ss,13,false,MASKF)                     \
    STEP16(ss,14,false,MASKF) STEP16(ss,15,false,MASKF)

#define STOREROWS2(ss)                                                      \
  {                                                                         \
    ushort* Ww = W + ((size_t)b*TT + (size_t)(ss)*16) * LPADH;              \
    _Pragma("unroll")                                                       \
    for (int j=0;j<16;++j)                                                  \
      *reinterpret_cast<uint2*>(Ww + (size_t)j*LPADH + 4*l)                 \
          = make_uint2(sbLo[j], sbHi[j]);                                   \
    if (is63) {                                                             \
      uint4 pk0, pk1;                                                       \
      pk0.x = pk_bf16(s4f[0], s4f[1]);   pk0.y = pk_bf16(s4f[2], s4f[3]);   \
      pk0.z = pk_bf16(s4f[4], s4f[5]);   pk0.w = pk_bf16(s4f[6], s4f[7]);   \
      pk1.x = pk_bf16(s4f[8], s4f[9]);   pk1.y = pk_bf16(s4f[10], s4f[11]); \
      pk1.z = pk_bf16(s4f[12], s4f[13]); pk1.w = pk_bf16(s4f[14], s4f[15]); \
      ushort* w4p = W4 + (size_t)b*TT + (size_t)(ss)*16;                    \
      *reinterpret_cast<uint4*>(w4p)     = pk0;                             \
      *reinterpret_cast<uint4*>(w4p + 8) = pk1;                             \
    }                                                                       \
  }

    LOADPX(wv)                       // preload my first owned slot's columns

    for (int s = 0; s < 32; ++s) {
        if ((s & 1) == wv) {
            // ---- owner: recursion core only ----
            if (s > 0) {
                float4 v = st4[l];
                a0 = v.x; a1 = v.y; a2 = v.z; a3 = v.w;
                a4 = st1[l];
                scNext = scSh[0];
            }
            if (s == 0)      { RG2(0, true,  false) }
            else if (s < 24) { RG2(s, false, false) }
            else             { RG2(s, false, true ) }
            st4[l] = make_float4(a0, a1, a2, a3);
            st1[l] = a4;
            if (l == 0) scSh[0] = scNext;
        } else {
            // ---- off-phase: issue next slot's loads first, then store ----
            if (s >= 1 && s < 31) LOADPX(s+1)
            if (s >= 1) STOREROWS2(s-1)
        }
        lds_barrier();   // LDS-handoff order only; vmem stays in flight
    }
    if (wv == 1) STOREROWS2(31)      // last slot's rows

#undef STEP16
#undef RG2
#undef STOREROWS2
#undef LOADPX
}

__global__ __launch_bounds__(128, 1)
void ctc_scan(const float* __restrict__ Px, const int* __restrict__ seqg,
              ushort* __restrict__ Wa, ushort* __restrict__ Wb,
              ushort* __restrict__ W4a, ushort* __restrict__ W4b,
              int* __restrict__ Eb)
{
    const int bx = blockIdx.x;
    const int wv = threadIdx.x >> 6, l = threadIdx.x & 63;
    if (bx < BB) scan_body<false>(bx,      wv, l, Px, seqg, Wa, W4a, Eb);
    else         scan_body<true >(bx - BB, wv, l, Px, seqg, Wb, W4b, Eb);
}

// ============== combine: r15 verbatim (exponent/mantissa logs) ==============
__global__ __launch_bounds__(64)
void ctc_combine(const ushort* __restrict__ Wa, const ushort* __restrict__ Wb,
                 const ushort* __restrict__ W4a, const ushort* __restrict__ W4b,
                 const int* __restrict__ Eb, const int* __restrict__ seqg,
                 double* __restrict__ Lq)
{
    const int b = blockIdx.x, q = blockIdx.y, l = threadIdx.x;
    const bool is63 = (l == 63);
    const int* sq = seqg + b*SS;
    const int r1 = sq[SS-1-2*l], r3 = sq[SS-2-2*l];
    const int ip = (l==0) ? 0 : (SS-2*l);
    const float m1 = (l==0) ? 1.f : ((r1 != sq[ip]) ? 1.f : 0.f);
    const float m3 = (r3 != r1) ? 1.f : 0.f;
    const int tm0=(4*l+769)>>1, tm1=(4*l+770)>>1, tm2=(4*l+771)>>1, tm3=(4*l+772)>>1;

    const ushort* WaB = Wa + (size_t)b*TT*LPADH;
    const ushort* WbB = Wb + (size_t)b*TT*LPADH;
    const ushort* W4aB = W4a + (size_t)b*TT;
    const ushort* W4bB = W4b + (size_t)b*TT;
    const int t0 = q*8;

    float Rcur;
    {
        const ushort* rw = WbB + (size_t)(TT-1-t0)*LPADH;
        uint2 xu = *reinterpret_cast<const uint2*>(rw + 4*l);
        float rnp = (up_lo(xu.x)+up_hi(xu.x))+(up_lo(xu.y)+up_hi(xu.y));
        if (is63) rnp += up_us(W4bB[TT-1-t0]);
        Rcur = full64f(rnp);
    }

    float PmN = 1.f, PmD = 1.f;
    int   Ei  = 0;

    #pragma unroll
    for (int k=0; k<8; ++k) {
        const int t = t0 + k;
        const int i = TT-1-t;
        const ushort* arow = WaB + (size_t)t*LPADH;
        uint2 au = *reinterpret_cast<const uint2*>(arow + (252 - 4*l));
        float av0 = up_lo(au.x), av1 = up_hi(au.x);
        float av2 = up_lo(au.y), av3 = up_hi(au.y);
        float a256 = up_us(W4aB[t]);
        float ar4 = shfl_up1_f32(av0);
        if (l == 0) ar4 = a256;

        float u0,u1,u2,u3,u4, rnext = 0.f;
        if (i > 0) {
            const ushort* rw = WbB + (size_t)(i-1)*LPADH;
            uint2 bu = *reinterpret_cast<const uint2*>(rw + 4*l);
            float bv0 = up_lo(bu.x), bv1 = up_hi(bu.x);
            float bv2 = up_lo(bu.y), bv3 = up_hi(bu.y);
            float b4 = up_us(W4bB[i-1]);
            float e3u = shfl_up1_f32(bv3);
            u0 = bv0 + e3u;
            u1 = (bv1 + bv0) + m1*e3u;
            u2 = bv2 + bv1;
            u3 = (bv3 + bv2) + m3*bv1;
            u4 = b4 + bv3;
            if (i >= TT - SS) {
                if (i >= tm0) u0 = 0.f;
                if (i >= tm1) u1 = 0.f;
                if (i >= tm2) u2 = 0.f;
                if (i >= tm3) u3 = 0.f;
            }
            rnext = (bv0+bv1)+(bv2+bv3);
            if (is63) rnext += b4;
        } else {
            u0 = (l==0)?1.f:0.f; u1 = u0; u2=0.f; u3=0.f; u4=0.f;
        }
        float trp = ar4*u0 + av3*u1 + av2*u2 + av1*u3;
        if (is63) trp += av0*u4;
        float sap = (av1 + av2) + (av3 + ar4);
        if (is63) sap += av0;

        float D  = full64f(trp);
        float S  = full64f(sap);
        float Rn = full64f(rnext);
        if (is63) {
            float dd = fmaxf(D, 1e-37f);
            uint bn = __builtin_bit_cast(uint, dd);
            Ei += (int)((bn >> 23) & 0xFFu) - 127;
            PmN *= __builtin_bit_cast(float, (bn & 0x807FFFFFu) | (127u<<23));
            float sr = fmaxf(S * Rcur, 1e-37f);
            uint bd = __builtin_bit_cast(uint, sr);
            Ei -= (int)((bd >> 23) & 0xFFu) - 127;
            PmD *= __builtin_bit_cast(float, (bd & 0x807FFFFFu) | (127u<<23));
            if (i > 0 && (i & 7) == 0) Ei -= Eb[b*64 + (i>>3)];
        }
        Rcur = Rn;
    }
    if (is63)
        Lq[b*64 + q] = log((double)PmN / (double)PmD) + (double)Ei * M_LN2;
}

__global__ __launch_bounds__(256)
void ctc_final(const double* __restrict__ Lq, float* __restrict__ out)
{
    const int t = threadIdx.x;
    double v = 0.0;
    #pragma unroll
    for (int k=0;k<32;++k) v += Lq[t + 256*k];
    double s = full64d(v);
    __shared__ double w[4];
    if ((t & 63) == 63) w[t>>6] = s;
    __syncthreads();
    if (t == 0) out[0] = (float)(-(w[0]+w[1]+w[2]+w[3]));
}

extern "C" void kernel_launch(void* const* d_in, const int* in_sizes, int n_in,
                              void* d_out, int out_size, void* d_ws, size_t ws_size,
                              hipStream_t stream)
{
    const float* P     = (const float*)d_in[0];   // params (B,C,T) fp32
    const int*   seq   = (const int*)  d_in[1];   // (B,S) int32
    // d_in[2] = lengths (unused by the reference computation)
    const int*   blank = (const int*)  d_in[3];   // scalar int

    // ws layout: Wa | Wb (34.1 MB bf16 each) | W4a | W4b | Lq | Eb | Px (fp32)
    ushort* Wa  = (ushort*)d_ws;
    ushort* Wb  = Wa  + (size_t)BB*TT*LPADH;
    ushort* W4a = Wb  + (size_t)BB*TT*LPADH;      // BB*TT ushorts (128 KB)
    ushort* W4b = W4a + (size_t)BB*TT;
    double* Lq  = (double*)(W4b + (size_t)BB*TT); // 8192 doubles
    int*    Eb  = (int*)(Lq + (size_t)BB*64);     // 8192 ints
    float*  Px  = (float*)(Eb + (size_t)BB*64);   // BB*TT*PXW floats (34.6 MB)
    (void)ws_size; (void)in_sizes; (void)n_in; (void)out_size;

    ctc_xpose<<<dim3(BB, 8), 256, 0, stream>>>(P, seq, blank, Px);
    ctc_scan<<<2*BB, 128, 0, stream>>>(Px, seq, Wa, Wb, W4a, W4b, Eb);
    ctc_combine<<<dim3(BB, 64), 64, 0, stream>>>(Wa, Wb, W4a, W4b, Eb, seq, Lq);
    ctc_final<<<1, 256, 0, stream>>>(Lq, (float*)d_out);
}

// Round 20
// 58.759 us; speedup vs baseline: 1.1819x; 1.1819x over previous
//
#include <hip/hip_runtime.h>
#include <math.h>

// CTC loss (per-step-normalized fwd/bwd), B=128, C=512, T=512, S=128, L=257.
// Round-20: r18 base (best passing, 58.3us; direct-P float4 gathers -- r19
// proved the scan is insensitive to load layout: coalesced Px gave +0 on the
// scan) + 32-step slots (16 barriers vs 32). The only lever that has moved
// the scan since r15 is slot granularity/overhead (r17: 8->16 steps = -3us;
// r18: drain removal = -4us) -- halve the per-slot machinery once more.
// Off-phase issues loads before stores (r19's one good idea).
// Combine/final: r15 verbatim. Identity (r4-r18): lh_t = sigma*D/(S*R).
// bf16 rows; fp64 block accumulation; clamps -> no NaN possible.

#define BB 128
#define CC 512
#define TT 512
#define SS 128
#define LL 257
#define LPADH 260   // bf16 (ushort) elements per row

typedef unsigned int  uint;
typedef unsigned short ushort;

// ---- fp32 DPP helpers (gfx9 controls; validated on gfx950 rounds 3-19) ----
template<int CTRL>
__device__ __forceinline__ float dpp0_f32(float x){
    int v = __builtin_bit_cast(int, x);
    int r = __builtin_amdgcn_update_dpp(0, v, CTRL, 0xF, 0xF, true);
    return __builtin_bit_cast(float, r);
}
__device__ __forceinline__ float shfl_up1_f32(float x){ return dpp0_f32<0x138>(x); }
__device__ __forceinline__ float red8f(float x){
    x += dpp0_f32<0x111>(x);
    x += dpp0_f32<0x112>(x);
    x += dpp0_f32<0x114>(x);
    return x;
}
__device__ __forceinline__ float tail3f(float x){
    x += dpp0_f32<0x118>(x);
    x += dpp0_f32<0x142>(x);
    x += dpp0_f32<0x143>(x);
    return x;
}
__device__ __forceinline__ float full64f(float x){ return tail3f(red8f(x)); }
__device__ __forceinline__ float readlane63_f32(float x){
    int v = __builtin_bit_cast(int, x);
    return __builtin_bit_cast(float, __builtin_amdgcn_readlane(v, 63));
}
__device__ __forceinline__ float pow2if(int e){
    return __builtin_bit_cast(float, (127 + e) << 23);
}
// pack two fp32 -> bf16 pair via one v_perm_b32 (truncation)
__device__ __forceinline__ uint pk_bf16(float lo, float hi){
    return __builtin_amdgcn_perm(__builtin_bit_cast(uint, hi),
                                 __builtin_bit_cast(uint, lo), 0x07060302u);
}
__device__ __forceinline__ float up_lo(uint u){ return __builtin_bit_cast(float, u << 16); }
__device__ __forceinline__ float up_hi(uint u){ return __builtin_bit_cast(float, u & 0xFFFF0000u); }
__device__ __forceinline__ float up_us(ushort u){ return __builtin_bit_cast(float, ((uint)u) << 16); }
template<int CTRL>
__device__ __forceinline__ double dpp0_f64(double x){
    int2 v = __builtin_bit_cast(int2, x);
    int2 r;
    r.x = __builtin_amdgcn_update_dpp(0, v.x, CTRL, 0xF, 0xF, true);
    r.y = __builtin_amdgcn_update_dpp(0, v.y, CTRL, 0xF, 0xF, true);
    return __builtin_bit_cast(double, r);
}
__device__ __forceinline__ double full64d(double x){
    x += dpp0_f64<0x111>(x); x += dpp0_f64<0x112>(x); x += dpp0_f64<0x114>(x);
    x += dpp0_f64<0x118>(x); x += dpp0_f64<0x142>(x); x += dpp0_f64<0x143>(x);
    return x;
}

// LDS-only barrier (r18): order the state handoff without draining vmem.
__device__ __forceinline__ void lds_barrier(){
    asm volatile("s_waitcnt lgkmcnt(0)" ::: "memory");
    __builtin_amdgcn_s_barrier();
    __builtin_amdgcn_sched_barrier(0);
    asm volatile("" ::: "memory");
}

// ====== 2-wave producer/consumer scan; 32-step slots; float4 gathers ======
template<bool REV>
__device__ __forceinline__ void scan_body(
    int b, int wv, int l, const float* __restrict__ P,
    const int* __restrict__ seqg, int blank,
    ushort* __restrict__ W, ushort* __restrict__ W4, int* __restrict__ Eb)
{
    __shared__ float4 st4[64];
    __shared__ float  st1[64];
    __shared__ float  scSh[1];

    const bool is63 = (l == 63);
    const float* Pb = P + (size_t)b * (CC*TT);
    const int* sq = seqg + b*SS;

    float m1, m3;
    if (!REV) {
        int r1 = sq[2*l], r3 = sq[2*l+1];
        int ip = (l==0) ? 0 : (2*l-1);
        m1 = (l==0) ? 1.f : ((r1 != sq[ip]) ? 1.f : 0.f);
        m3 = (r3 != r1) ? 1.f : 0.f;
    } else {
        int r1 = sq[SS-1-2*l], r3 = sq[SS-2-2*l];
        int ip = (l==0) ? 0 : (SS-2*l);
        m1 = (l==0) ? 1.f : ((r1 != sq[ip]) ? 1.f : 0.f);
        m3 = (r3 != r1) ? 1.f : 0.f;
    }
    const int rr1 = REV ? sq[SS-1-2*l] : sq[2*l];
    const int rr3 = REV ? sq[SS-2-2*l] : sq[2*l+1];
    const float* pBp = Pb + (size_t)blank*TT;
    const float* p1p = Pb + (size_t)rr1*TT;
    const float* p3p = Pb + (size_t)rr3*TT;
    int* EbB = Eb + b*64;

    const int tm0=(4*l+769)>>1, tm1=(4*l+770)>>1, tm2=(4*l+771)>>1, tm3=(4*l+772)>>1;

    float a0=0.f,a1=0.f,a2=0.f,a3=0.f,a4=0.f;
    float scNext = 1.f, Sfull = 0.f;
    const float u0i = (l==0) ? 1.f : 0.f;
    float4 qB[8], q1[8], q3[8];           // 32 columns (one slot), float4 chunks
    uint sbLo[32], sbHi[32]; float s4f[32];

#define COMP4(v,c) ((c)==0?(v).x:((c)==1?(v).y:((c)==2?(v).z:(v).w)))

// load the 8 float4 column-chunks (per row) covering slot ss (steps 32ss..32ss+31)
#define LOADPG3(ss)                                                         \
  { _Pragma("unroll")                                                       \
    for (int k=0;k<8;++k){                                                  \
      const int c_ = REV ? (TT - 4 - 32*(ss) - 4*k) : (32*(ss) + 4*k);      \
      qB[k] = *reinterpret_cast<const float4*>(pBp + c_);                   \
      q1[k] = *reinterpret_cast<const float4*>(p1p + c_);                   \
      q3[k] = *reinterpret_cast<const float4*>(p3p + c_);                   \
    } }

#define STEP32(ss, j, FIRSTF, MASKF)                                        \
  {                                                                         \
    const int i = 32*(ss) + (j);                                            \
    float u0,u1,u2,u3,u4;                                                   \
    if (FIRSTF) { u0=u0i; u1=u0i; u2=0.f; u3=0.f; u4=0.f; }                 \
    else {                                                                  \
      float e3u = shfl_up1_f32(a3);                                         \
      u0 = a0 + e3u; u1 = (a1+a0) + m1*e3u; u2 = a2+a1;                     \
      u3 = (a3+a2) + m3*a1; u4 = a4+a3;                                     \
      if (MASKF) {                                                          \
        if (i >= tm0) u0 = 0.f;                                             \
        if (i >= tm1) u1 = 0.f;                                             \
        if (i >= tm2) u2 = 0.f;                                             \
        if (i >= tm3) u3 = 0.f;                                             \
      }                                                                     \
    }                                                                       \
    constexpr int ch_ = (j) >> 2;                                           \
    constexpr int cm_ = REV ? ((3-(j)) & 3) : ((j) & 3);                    \
    float pB = COMP4(qB[ch_], cm_);                                         \
    float pq = COMP4(q1[ch_], cm_);                                         \
    float pr = COMP4(q3[ch_], cm_);                                         \
    if (((j)&7)==0) { pB*=scNext; pq*=scNext; pr*=scNext; }                 \
    float n0=u0*pB, n1=u1*pq, n2=u2*pB, n3=u3*pr, n4=u4*pB;                 \
    sbLo[j]=pk_bf16(n0,n1); sbHi[j]=pk_bf16(n2,n3); s4f[j]=n4;              \
    if (((j)&7)==5) {                                                       \
      float part=(n0+n1)+(n2+n3); if (is63) part+=n4;                       \
      Sfull = full64f(part);                                                \
    }                                                                       \
    if (((j)&7)==7) {                                                       \
      float Su = readlane63_f32(Sfull);                                     \
      int ex = (__builtin_bit_cast(int, Su) >> 23) & 0xFF;                  \
      int e = (ex==0) ? 0 : (ex-127);                                       \
      e = e < -120 ? -120 : (e > 120 ? 120 : e);                            \
      scNext = pow2if(-e);                                                  \
      const int g_ = i >> 3;                                                \
      if (REV && l==0 && g_+1 < 64) EbB[g_+1] = e;                          \
    }                                                                       \
    a0=n0; a1=n1; a2=n2; a3=n3; a4=n4;                                      \
  }

#define RG3(ss, FIRSTF, MASKF)                                              \
    STEP32(ss,0,FIRSTF,MASKF)  STEP32(ss,1,false,MASKF)                     \
    STEP32(ss,2,false,MASKF)   STEP32(ss,3,false,MASKF)                     \
    STEP32(ss,4,false,MASKF)   STEP32(ss,5,false,MASKF)                     \
    STEP32(ss,6,false,MASKF)   STEP32(ss,7,false,MASKF)                     \
    STEP32(ss,8,false,MASKF)   STEP32(ss,9,false,MASKF)                     \
    STEP32(ss,10,false,MASKF)  STEP32(ss,11,false,MASKF)                    \
    STEP32(ss,12,false,MASKF)  STEP32(ss,13,false,MASKF)                    \
    STEP32(ss,14,false,MASKF)  STEP32(ss,15,false,MASKF)                    \
    STEP32(ss,16,false,MASKF)  STEP32(ss,17,false,MASKF)                    \
    STEP32(ss,18,false,MASKF)  STEP32(ss,19,false,MASKF)                    \
    STEP32(ss,20,false,MASKF)  STEP32(ss,21,false,MASKF)                    \
    STEP32(ss,22,false,MASKF)  STEP32(ss,23,false,MASKF)                    \
    STEP32(ss,24,false,MASKF)  STEP32(ss,25,false,MASKF)                    \
    STEP32(ss,26,false,MASKF)  STEP32(ss,27,false,MASKF)                    \
    STEP32(ss,28,false,MASKF)  STEP32(ss,29,false,MASKF)                    \
    STEP32(ss,30,false,MASKF)  STEP32(ss,31,false,MASKF)

#define STOREROWS3(ss)                                                      \
  {                                                                         \
    ushort* Ww = W + ((size_t)b*TT + (size_t)(ss)*32) * LPADH;              \
    _Pragma("unroll")                                                       \
    for (int j=0;j<32;++j)                                                  \
      *reinterpret_cast<uint2*>(Ww + (size_t)j*LPADH + 4*l)                 \
          = make_uint2(sbLo[j], sbHi[j]);                                   \
    if (is63) {                                                             \
      ushort* w4p = W4 + (size_t)b*TT + (size_t)(ss)*32;                    \
      _Pragma("unroll")                                                     \
      for (int g=0;g<4;++g) {                                               \
        uint4 pk;                                                           \
        pk.x = pk_bf16(s4f[8*g+0], s4f[8*g+1]);                             \
        pk.y = pk_bf16(s4f[8*g+2], s4f[8*g+3]);                             \
        pk.z = pk_bf16(s4f[8*g+4], s4f[8*g+5]);                             \
        pk.w = pk_bf16(s4f[8*g+6], s4f[8*g+7]);                             \
        *reinterpret_cast<uint4*>(w4p + 8*g) = pk;                          \
      }                                                                     \
    }                                                                       \
  }

    LOADPG3(wv)                      // preload my first owned slot's columns

    for (int s = 0; s < 16; ++s) {
        if ((s & 1) == wv) {
            // ---- owner: recursion core only ----
            if (s > 0) {
                float4 v = st4[l];
                a0 = v.x; a1 = v.y; a2 = v.z; a3 = v.w;
                a4 = st1[l];
                scNext = scSh[0];
            }
            if (s == 0)      { RG3(0, true,  false) }
            else if (s < 12) { RG3(s, false, false) }
            else             { RG3(s, false, true ) }
            st4[l] = make_float4(a0, a1, a2, a3);
            st1[l] = a4;
            if (l == 0) scSh[0] = scNext;
        } else {
            // ---- off-phase: issue next slot's loads first, then store ----
            if (s < 15) LOADPG3(s+1)
            if (s >= 1) STOREROWS3(s-1)
        }
        lds_barrier();   // LDS-handoff order only; vmem stays in flight
    }
    if (wv == 1) STOREROWS3(15)      // last slot's rows

#undef STEP32
#undef RG3
#undef STOREROWS3
#undef LOADPG3
#undef COMP4
}

__global__ __launch_bounds__(128, 1)
void ctc_scan(const float* __restrict__ P, const int* __restrict__ seqg,
              const int* __restrict__ blankp, ushort* __restrict__ Wa,
              ushort* __restrict__ Wb, ushort* __restrict__ W4a,
              ushort* __restrict__ W4b, int* __restrict__ Eb)
{
    const int bx = blockIdx.x;
    const int wv = threadIdx.x >> 6, l = threadIdx.x & 63;
    const int blank = blankp[0];
    if (bx < BB) scan_body<false>(bx,      wv, l, P, seqg, blank, Wa, W4a, Eb);
    else         scan_body<true >(bx - BB, wv, l, P, seqg, blank, Wb, W4b, Eb);
}

// ============== combine: r15 verbatim (exponent/mantissa logs) ==============
__global__ __launch_bounds__(64)
void ctc_combine(const ushort* __restrict__ Wa, const ushort* __restrict__ Wb,
                 const ushort* __restrict__ W4a, const ushort* __restrict__ W4b,
                 const int* __restrict__ Eb, const int* __restrict__ seqg,
                 double* __restrict__ Lq)
{
    const int b = blockIdx.x, q = blockIdx.y, l = threadIdx.x;
    const bool is63 = (l == 63);
    const int* sq = seqg + b*SS;
    const int r1 = sq[SS-1-2*l], r3 = sq[SS-2-2*l];
    const int ip = (l==0) ? 0 : (SS-2*l);
    const float m1 = (l==0) ? 1.f : ((r1 != sq[ip]) ? 1.f : 0.f);
    const float m3 = (r3 != r1) ? 1.f : 0.f;
    const int tm0=(4*l+769)>>1, tm1=(4*l+770)>>1, tm2=(4*l+771)>>1, tm3=(4*l+772)>>1;

    const ushort* WaB = Wa + (size_t)b*TT*LPADH;
    const ushort* WbB = Wb + (size_t)b*TT*LPADH;
    const ushort* W4aB = W4a + (size_t)b*TT;
    const ushort* W4bB = W4b + (size_t)b*TT;
    const int t0 = q*8;

    float Rcur;
    {
        const ushort* rw = WbB + (size_t)(TT-1-t0)*LPADH;
        uint2 xu = *reinterpret_cast<const uint2*>(rw + 4*l);
        float rnp = (up_lo(xu.x)+up_hi(xu.x))+(up_lo(xu.y)+up_hi(xu.y));
        if (is63) rnp += up_us(W4bB[TT-1-t0]);
        Rcur = full64f(rnp);
    }

    float PmN = 1.f, PmD = 1.f;
    int   Ei  = 0;

    #pragma unroll
    for (int k=0; k<8; ++k) {
        const int t = t0 + k;
        const int i = TT-1-t;
        const ushort* arow = WaB + (size_t)t*LPADH;
        uint2 au = *reinterpret_cast<const uint2*>(arow + (252 - 4*l));
        float av0 = up_lo(au.x), av1 = up_hi(au.x);
        float av2 = up_lo(au.y), av3 = up_hi(au.y);
        float a256 = up_us(W4aB[t]);
        float ar4 = shfl_up1_f32(av0);
        if (l == 0) ar4 = a256;

        float u0,u1,u2,u3,u4, rnext = 0.f;
        if (i > 0) {
            const ushort* rw = WbB + (size_t)(i-1)*LPADH;
            uint2 bu = *reinterpret_cast<const uint2*>(rw + 4*l);
            float bv0 = up_lo(bu.x), bv1 = up_hi(bu.x);
            float bv2 = up_lo(bu.y), bv3 = up_hi(bu.y);
            float b4 = up_us(W4bB[i-1]);
            float e3u = shfl_up1_f32(bv3);
            u0 = bv0 + e3u;
            u1 = (bv1 + bv0) + m1*e3u;
            u2 = bv2 + bv1;
            u3 = (bv3 + bv2) + m3*bv1;
            u4 = b4 + bv3;
            if (i >= TT - SS) {
                if (i >= tm0) u0 = 0.f;
                if (i >= tm1) u1 = 0.f;
                if (i >= tm2) u2 = 0.f;
                if (i >= tm3) u3 = 0.f;
            }
            rnext = (bv0+bv1)+(bv2+bv3);
            if (is63) rnext += b4;
        } else {
            u0 = (l==0)?1.f:0.f; u1 = u0; u2=0.f; u3=0.f; u4=0.f;
        }
        float trp = ar4*u0 + av3*u1 + av2*u2 + av1*u3;
        if (is63) trp += av0*u4;
        float sap = (av1 + av2) + (av3 + ar4);
        if (is63) sap += av0;

        float D  = full64f(trp);
        float S  = full64f(sap);
        float Rn = full64f(rnext);
        if (is63) {
            float dd = fmaxf(D, 1e-37f);
            uint bn = __builtin_bit_cast(uint, dd);
            Ei += (int)((bn >> 23) & 0xFFu) - 127;
            PmN *= __builtin_bit_cast(float, (bn & 0x807FFFFFu) | (127u<<23));
            float sr = fmaxf(S * Rcur, 1e-37f);
            uint bd = __builtin_bit_cast(uint, sr);
            Ei -= (int)((bd >> 23) & 0xFFu) - 127;
            PmD *= __builtin_bit_cast(float, (bd & 0x807FFFFFu) | (127u<<23));
            if (i > 0 && (i & 7) == 0) Ei -= Eb[b*64 + (i>>3)];
        }
        Rcur = Rn;
    }
    if (is63)
        Lq[b*64 + q] = log((double)PmN / (double)PmD) + (double)Ei * M_LN2;
}

__global__ __launch_bounds__(256)
void ctc_final(const double* __restrict__ Lq, float* __restrict__ out)
{
    const int t = threadIdx.x;
    double v = 0.0;
    #pragma unroll
    for (int k=0;k<32;++k) v += Lq[t + 256*k];
    double s = full64d(v);
    __shared__ double w[4];
    if ((t & 63) == 63) w[t>>6] = s;
    __syncthreads();
    if (t == 0) out[0] = (float)(-(w[0]+w[1]+w[2]+w[3]));
}

extern "C" void kernel_launch(void* const* d_in, const int* in_sizes, int n_in,
                              void* d_out, int out_size, void* d_ws, size_t ws_size,
                              hipStream_t stream)
{
    const float* P     = (const float*)d_in[0];   // params (B,C,T) fp32
    const int*   seq   = (const int*)  d_in[1];   // (B,S) int32
    // d_in[2] = lengths (unused by the reference computation)
    const int*   blank = (const int*)  d_in[3];   // scalar int

    // ws layout (bf16 rows): Wa | Wb (34.1 MB each) | W4a | W4b | Lq | Eb
    ushort* Wa  = (ushort*)d_ws;
    ushort* Wb  = Wa  + (size_t)BB*TT*LPADH;
    ushort* W4a = Wb  + (size_t)BB*TT*LPADH;      // BB*TT ushorts (128 KB)
    ushort* W4b = W4a + (size_t)BB*TT;
    double* Lq  = (double*)(W4b + (size_t)BB*TT); // 8192 doubles
    int*    Eb  = (int*)(Lq + (size_t)BB*64);     // 8192 ints
    (void)ws_size; (void)in_sizes; (void)n_in; (void)out_size;

    ctc_scan<<<2*BB, 128, 0, stream>>>(P, seq, blank, Wa, Wb, W4a, W4b, Eb);
    ctc_combine<<<dim3(BB, 64), 64, 0, stream>>>(Wa, Wb, W4a, W4b, Eb, seq, Lq);
    ctc_final<<<1, 256, 0, stream>>>(Lq, (float*)d_out);
}